// Round 12
// baseline (390.808 us; speedup 1.0000x reference)
//
#include <hip/hip_runtime.h>

// MHA fused pipeline for MI355X (gfx950), f16 MFMA + fp32 accumulate.
// Round 19 == Round 18 with compile fix (stray "#pragma unroll" before a
// closing brace in attn's softmax loop -> "expected statement").
//  - attn: R16 body + bit-exact T13 defer-max (skip O-rescale when
//    __all(mx <= m_i); alpha==1 on that path).
//  - cvt fusion: cvt_x + both cvt_wt merged into ONE cvt_all_kernel
//    (8192 blocks, block-uniform branch). 6 launches -> 4.
//  - gemm_qkv: unchanged (123us, MfmaUtil 35 -- parked).
//  - gemm_out: 256x128 1-barrier, 256 blocks = 1 round.
//
// ws layout (bytes):
//   xh     @ 0          : 4096x2048 f16  (x cast)
//   wqkvt  @ 16777216   : 6144x2048 f16  (Wqkv^T)   [dead after QKV gemm]
//   Oh     @ 16777216   : 4096x2048 f16  (attn out)  [overlays wqkvt]
//   Qh     @ 41943040   : [64 bh][2048][64] f16  (RoPE'd)
//   Kh     @ 58720256   : [64 bh][2048][64] f16  (RoPE'd)
//   Vth    @ 75497472   : [64 bh][64][2048] f16  (V^T)
//   woutt  @ 92274688   : 2048x2048 f16  (Wout^T)
//   total 100663296 B = 96 MB

typedef _Float16 half8 __attribute__((ext_vector_type(8)));
typedef _Float16 half4 __attribute__((ext_vector_type(4)));
typedef float floatx4 __attribute__((ext_vector_type(4)));

#define GLD_LDS16(gp, sp)                                        \
  __builtin_amdgcn_global_load_lds(                              \
      (__attribute__((address_space(1))) void*)(gp),             \
      (__attribute__((address_space(3))) void*)(sp), 16, 0, 0)

__device__ __forceinline__ floatx4 mfma16(half8 a, half8 b, floatx4 c) {
  return __builtin_amdgcn_mfma_f32_16x16x32_f16(a, b, c, 0, 0, 0);
}
__device__ __forceinline__ floatx4 mfma16k16(half4 a, half4 b, floatx4 c) {
  return __builtin_amdgcn_mfma_f32_16x16x16f16(a, b, c, 0, 0, 0);
}

// ------------------------------------------------------- fused cvt kernel
// blocks [0,4096):    x f32 -> xh f16 (8 elems/thread)
// blocks [4096,7168):  Wqkv (2048x6144) -> wqkvt (6144x2048) f16, 64x64 tiles
// blocks [7168,8192):  Wout (2048x2048) -> woutt (2048x2048) f16
__global__ __launch_bounds__(256) void cvt_all_kernel(
    const float* __restrict__ x, _Float16* __restrict__ xh,
    const float* __restrict__ Wqkv, _Float16* __restrict__ wqkvt,
    const float* __restrict__ Wout, _Float16* __restrict__ woutt) {
  __shared__ float tile[64][65];
  int b = blockIdx.x, tid = threadIdx.x;
  if (b < 4096) {
    int idx = b * 256 + tid;
    const floatx4* p = (const floatx4*)x + (size_t)idx * 2;
    floatx4 a = p[0], b2 = p[1];
    half8 o;
#pragma unroll
    for (int j = 0; j < 4; ++j) { o[j] = (_Float16)a[j]; o[4 + j] = (_Float16)b2[j]; }
    *((half8*)xh + idx) = o;
    return;
  }
  const float* W;
  _Float16* Wt;
  int Kd, Nd, n0, k0;
  if (b < 7168) {
    int bb = b - 4096;  // 96 x 32
    W = Wqkv; Wt = wqkvt; Kd = 2048; Nd = 6144;
    n0 = (bb % 96) * 64; k0 = (bb / 96) * 64;
  } else {
    int bb = b - 7168;  // 32 x 32
    W = Wout; Wt = woutt; Kd = 2048; Nd = 2048;
    n0 = (bb % 32) * 64; k0 = (bb / 32) * 64;
  }
#pragma unroll
  for (int it = 0; it < 4; ++it) {
    int r = (tid >> 4) + it * 16;   // k-local
    int c = (tid & 15) * 4;         // n-local
    floatx4 v = *(const floatx4*)(W + (size_t)(k0 + r) * Nd + n0 + c);
    tile[r][c + 0] = v[0]; tile[r][c + 1] = v[1];
    tile[r][c + 2] = v[2]; tile[r][c + 3] = v[3];
  }
  __syncthreads();
#pragma unroll
  for (int it = 0; it < 2; ++it) {
    int r = (tid >> 3) + it * 32;   // n-local
    int c = (tid & 7) * 8;          // k-local
    half8 o;
#pragma unroll
    for (int j = 0; j < 8; ++j) o[j] = (_Float16)tile[c + j][r];
    *(half8*)(Wt + (size_t)(n0 + r) * Kd + k0 + c) = o;
  }
}

// --------------------------------------------- 256x192 1-barrier GEMM (QKV)
// C(256x192) = A(4096x2048) @ Bt(6144x2048)^T + bias, QKV epilogue.
// 8 waves = 4M x 2N; grid 32x16 = 512 blocks = 2 full rounds.
// (Unchanged: 123us, MfmaUtil 35, conflicts 0.)
__global__ __launch_bounds__(512, 2) void gemm_qkv_kernel(
    const _Float16* __restrict__ A, const _Float16* __restrict__ Bt,
    const float* __restrict__ bias,
    _Float16* __restrict__ Qd, _Float16* __restrict__ Kkd,
    _Float16* __restrict__ Vd) {
  __shared__ __align__(16) _Float16 sA[2][16384];   // 256 x 64
  __shared__ __align__(16) _Float16 sB[2][12288];   // 192 x 64
  constexpr int KD = 2048;
  constexpr int NT = KD / 64;  // 32 K-tiles

  int tid = threadIdx.x, w = tid >> 6, l = tid & 63;
  int lr = l & 15, quad = l >> 4;
  int wr = w >> 1, wc = w & 1;
  int m0 = blockIdx.y * 256, n0 = blockIdx.x * 192;

  int csw0 = ((quad) ^ (lr & 7)) * 8;
  int csw1 = ((quad + 4) ^ (lr & 7)) * 8;

  const _Float16* pA[4];
  const _Float16* pB[3];
  {
    int rl = l >> 3;
    int cs = ((l & 7) ^ rl) * 8;
#pragma unroll
    for (int jj = 0; jj < 4; ++jj)
      pA[jj] = A + (size_t)(m0 + w * 32 + jj * 8 + rl) * KD + cs;
#pragma unroll
    for (int jj = 0; jj < 3; ++jj)
      pB[jj] = Bt + (size_t)(n0 + w * 24 + jj * 8 + rl) * KD + cs;
  }

#define STAGE_ALL(BUF, KT)                                                   \
  _Pragma("unroll") for (int jj = 0; jj < 4; ++jj)                           \
    GLD_LDS16(pA[jj] + (KT), &sA[BUF][(w * 32 + jj * 8) * 64]);              \
  _Pragma("unroll") for (int jj = 0; jj < 3; ++jj)                           \
    GLD_LDS16(pB[jj] + (KT), &sB[BUF][(w * 24 + jj * 8) * 64]);

  floatx4 z4 = {0.f, 0.f, 0.f, 0.f};
  floatx4 acc[4][6];
#pragma unroll
  for (int i = 0; i < 4; ++i)
#pragma unroll
    for (int j = 0; j < 6; ++j) acc[i][j] = z4;

  STAGE_ALL(0, 0);
  asm volatile("s_waitcnt vmcnt(0)" ::: "memory");
  __builtin_amdgcn_s_barrier();

  half8 af[4][2], bf[6][2];
#pragma unroll 2
  for (int t = 0; t < NT; ++t) {
    int buf = t & 1, nbuf = buf ^ 1;
    if (t + 1 < NT) { STAGE_ALL(nbuf, (t + 1) * 64); }
#pragma unroll
    for (int j = 0; j < 6; ++j) {
      int row_ = wc * 96 + j * 16 + lr;
      bf[j][0] = *(const half8*)&sB[buf][row_ * 64 + csw0];
      bf[j][1] = *(const half8*)&sB[buf][row_ * 64 + csw1];
    }
#pragma unroll
    for (int i = 0; i < 4; ++i) {
      int row_ = wr * 64 + i * 16 + lr;
      af[i][0] = *(const half8*)&sA[buf][row_ * 64 + csw0];
      af[i][1] = *(const half8*)&sA[buf][row_ * 64 + csw1];
    }
    __builtin_amdgcn_s_setprio(1);
#pragma unroll
    for (int j = 0; j < 6; ++j)
#pragma unroll
      for (int ks = 0; ks < 2; ++ks)
#pragma unroll
        for (int i = 0; i < 4; ++i)
          acc[i][j] = mfma16(af[i][ks], bf[j][ks], acc[i][j]);
    __builtin_amdgcn_s_setprio(0);
    asm volatile("s_waitcnt vmcnt(0)" ::: "memory");
    __builtin_amdgcn_s_barrier();
  }

  // ---- epilogue. C/D layout: col = lane&15, row = quad*4 + r.
  float bj[6];
#pragma unroll
  for (int j = 0; j < 6; ++j) bj[j] = bias[n0 + wc * 96 + j * 16 + lr];
  float freq = __expf(-(float)lr * 0.57564627324851148f);  // 10000^(-lr/16)
#pragma unroll
  for (int j = 0; j < 6; ++j) {
    int cb = wc * 96 + j * 16;
    int cg = n0 + cb;
    int which = cg >> 11;
    int d0 = cb & 63;  // n0 is 64-aligned (192*bx)
    int hh = (cg & 2047) >> 6;
    if (which == 2) {
      int dd = d0 + lr;
#pragma unroll
      for (int i = 0; i < 4; ++i) {
        int m = m0 + wr * 64 + i * 16 + quad * 4;
        int bb = m >> 11, tt = m & 2047;
        half4 h;
#pragma unroll
        for (int r = 0; r < 4; ++r) h[r] = (_Float16)(acc[i][j][r] + bj[j]);
        *(half4*)&Vd[(((size_t)(bb * 32 + hh)) * 64 + dd) * 2048 + tt] = h;
      }
    } else if (d0 == 0) {
      _Float16* dst = which ? Kkd : Qd;
#pragma unroll
      for (int i = 0; i < 4; ++i)
#pragma unroll
        for (int r = 0; r < 4; ++r) {
          int m = m0 + wr * 64 + i * 16 + quad * 4 + r;
          int bb = m >> 11, tt = m & 2047;
          float sn, cs2;
          __sincosf((float)tt * freq, &sn, &cs2);
          float x1 = acc[i][j][r] + bj[j];
          float x2 = acc[i][j + 1][r] + bj[j + 1];
          _Float16* row = dst + ((size_t)(bb * 32 + hh) * 2048 + (size_t)tt) * 64;
          row[lr] = (_Float16)(x1 * cs2 - x2 * sn);
          row[lr + 16] = (_Float16)(x1 * sn + x2 * cs2);
        }
    } else if (d0 >= 32) {
      _Float16* dst = which ? Kkd : Qd;
#pragma unroll
      for (int i = 0; i < 4; ++i)
#pragma unroll
        for (int r = 0; r < 4; ++r) {
          int m = m0 + wr * 64 + i * 16 + quad * 4 + r;
          int bb = m >> 11, tt = m & 2047;
          _Float16* row = dst + ((size_t)(bb * 32 + hh) * 2048 + (size_t)tt) * 64;
          row[d0 + lr] = (_Float16)(acc[i][j][r] + bj[j]);
        }
    }
  }
#undef STAGE_ALL
}

// --------------------------------------------- 256x128 1-barrier GEMM (out)
// Co(4096x2048 f32) = A(4096x2048) @ Bt(2048x2048)^T + bias.
// 8 waves = 4M x 2N (wave tile 64x64); grid 16x16 = 256 blocks = 1 round.
__global__ __launch_bounds__(512, 2) void gemm_out_kernel(
    const _Float16* __restrict__ A, const _Float16* __restrict__ Bt,
    const float* __restrict__ bias, float* __restrict__ Co) {
  __shared__ __align__(16) _Float16 sA[2][16384];  // 256 x 64
  __shared__ __align__(16) _Float16 sB[2][8192];   // 128 x 64
  constexpr int KD = 2048;
  constexpr int NT = KD / 64;

  int tid = threadIdx.x, w = tid >> 6, l = tid & 63;
  int lr = l & 15, quad = l >> 4;
  int wr = w >> 1, wc = w & 1;
  int m0 = blockIdx.y * 256, n0 = blockIdx.x * 128;

  int csw0 = ((quad) ^ (lr & 7)) * 8;
  int csw1 = ((quad + 4) ^ (lr & 7)) * 8;

  const _Float16* pA[4];
  const _Float16* pB[2];
  {
    int rl = l >> 3;
    int cs = ((l & 7) ^ rl) * 8;
#pragma unroll
    for (int jj = 0; jj < 4; ++jj)
      pA[jj] = A + (size_t)(m0 + w * 32 + jj * 8 + rl) * KD + cs;
#pragma unroll
    for (int jj = 0; jj < 2; ++jj)
      pB[jj] = Bt + (size_t)(n0 + w * 16 + jj * 8 + rl) * KD + cs;
  }

#define STAGE_O(BUF, KT)                                                     \
  _Pragma("unroll") for (int jj = 0; jj < 4; ++jj)                           \
    GLD_LDS16(pA[jj] + (KT), &sA[BUF][(w * 32 + jj * 8) * 64]);              \
  _Pragma("unroll") for (int jj = 0; jj < 2; ++jj)                           \
    GLD_LDS16(pB[jj] + (KT), &sB[BUF][(w * 16 + jj * 8) * 64]);

  floatx4 z4 = {0.f, 0.f, 0.f, 0.f};
  floatx4 acc[4][4];
#pragma unroll
  for (int i = 0; i < 4; ++i)
#pragma unroll
    for (int j = 0; j < 4; ++j) acc[i][j] = z4;

  STAGE_O(0, 0);
  asm volatile("s_waitcnt vmcnt(0)" ::: "memory");
  __builtin_amdgcn_s_barrier();

  half8 af[4][2], bf[4][2];
#pragma unroll 2
  for (int t = 0; t < NT; ++t) {
    int buf = t & 1, nbuf = buf ^ 1;
    if (t + 1 < NT) { STAGE_O(nbuf, (t + 1) * 64); }
#pragma unroll
    for (int j = 0; j < 4; ++j) {
      int row_ = wc * 64 + j * 16 + lr;
      bf[j][0] = *(const half8*)&sB[buf][row_ * 64 + csw0];
      bf[j][1] = *(const half8*)&sB[buf][row_ * 64 + csw1];
    }
#pragma unroll
    for (int i = 0; i < 4; ++i) {
      int row_ = wr * 64 + i * 16 + lr;
      af[i][0] = *(const half8*)&sA[buf][row_ * 64 + csw0];
      af[i][1] = *(const half8*)&sA[buf][row_ * 64 + csw1];
    }
    __builtin_amdgcn_s_setprio(1);
#pragma unroll
    for (int j = 0; j < 4; ++j)
#pragma unroll
      for (int ks = 0; ks < 2; ++ks)
#pragma unroll
        for (int i = 0; i < 4; ++i)
          acc[i][j] = mfma16(af[i][ks], bf[j][ks], acc[i][j]);
    __builtin_amdgcn_s_setprio(0);
    asm volatile("s_waitcnt vmcnt(0)" ::: "memory");
    __builtin_amdgcn_s_barrier();
  }

#pragma unroll
  for (int j = 0; j < 4; ++j) {
    int n = n0 + wc * 64 + j * 16 + lr;
    float bj = bias[n];
#pragma unroll
    for (int i = 0; i < 4; ++i)
#pragma unroll
      for (int r = 0; r < 4; ++r) {
        int m = m0 + wr * 64 + i * 16 + quad * 4 + r;
        Co[(size_t)m * 2048 + n] = acc[i][j][r] + bj;
      }
  }
#undef STAGE_O
}

// ---------------------------------------------------------------- attention
// Flash-style causal attention, S^T formulation + register prefetch.
// One 128-row q-tile per block; grid 64 x 16, qt = 15 - blockIdx.y (long
// blocks first); 3 blocks/CU (VGPR 148). R16 body + T13 defer-max (exact:
// skip O-rescale when __all(mx <= m_i), alpha==1 on that path).
__global__ __launch_bounds__(256) void attn_kernel(
    const _Float16* __restrict__ Q, const _Float16* __restrict__ Kk,
    const _Float16* __restrict__ Vt, _Float16* __restrict__ O) {
  constexpr int S = 2048;
  int bh = blockIdx.x;
  int qt = 15 - blockIdx.y;  // long blocks first
  int bb = bh >> 5, hh = bh & 31;
  const _Float16* Qb = Q + (size_t)bh * S * 64;
  const _Float16* Kb = Kk + (size_t)bh * S * 64;
  const _Float16* Vb = Vt + (size_t)bh * 64 * S;

  __shared__ __align__(16) _Float16 sK[128 * 72];   // [kv][64+pad], reused as sO
  __shared__ __align__(16) _Float16 sVt[64 * 136];  // [d][128+pad]

  int tid = threadIdx.x, w = tid >> 6, l = tid & 63;
  int lr = l & 15, quad = l >> 4;

  int rk = tid >> 3, ck = (tid & 7) * 8;   // K: 32 rows x 64d per pass
  int rv = tid >> 4, cv = (tid & 15) * 8;  // Vt: 16 rows x 128kv per pass
  const _Float16* Kst = Kb + (size_t)rk * 64 + ck;
  const _Float16* Vst = Vb + (size_t)rv * S + cv;

  floatx4 z4 = {0.f, 0.f, 0.f, 0.f};
  int q0 = qt * 128;

  half8 qf[2][2];  // [qtile][ks]
#pragma unroll
  for (int qtl = 0; qtl < 2; ++qtl)
#pragma unroll
    for (int ks = 0; ks < 2; ++ks) {
      half8 v = *(const half8*)(Qb + (size_t)(q0 + w * 32 + qtl * 16 + lr) * 64 +
                                ks * 32 + quad * 8);
      qf[qtl][ks] = v * (_Float16)0.18033688f;  // 0.125 * log2(e)
    }

  floatx4 Oa[4][2];
  float m_i[2] = {-1e30f, -1e30f}, l_i[2] = {0.f, 0.f};
#pragma unroll
  for (int dt = 0; dt < 4; ++dt)
#pragma unroll
    for (int qtl = 0; qtl < 2; ++qtl) Oa[dt][qtl] = z4;

  half8 kpre[4], vpre[4];
#pragma unroll
  for (int it = 0; it < 4; ++it) {
    kpre[it] = *(const half8*)(Kst + (size_t)it * 32 * 64);
    vpre[it] = *(const half8*)(Vst + (size_t)it * 16 * S);
  }

  for (int jt = 0; jt <= qt; ++jt) {
#pragma unroll
    for (int it = 0; it < 4; ++it) {
      *(half8*)&sK[(rk + it * 32) * 72 + ck] = kpre[it];
      *(half8*)&sVt[(rv + it * 16) * 136 + cv] = vpre[it];
    }
    if (jt < qt) {
      int kv1 = (jt + 1) * 128;
#pragma unroll
      for (int it = 0; it < 4; ++it) {
        kpre[it] = *(const half8*)(Kst + (size_t)(kv1 + it * 32) * 64);
        vpre[it] = *(const half8*)(Vst + kv1 + (size_t)it * 16 * S);
      }
    }
    __syncthreads();

    floatx4 Sa[2][8];
#pragma unroll
    for (int qtl = 0; qtl < 2; ++qtl)
#pragma unroll
      for (int kvt = 0; kvt < 8; ++kvt) Sa[qtl][kvt] = z4;
    __builtin_amdgcn_s_setprio(1);
#pragma unroll
    for (int ks = 0; ks < 2; ++ks) {
#pragma unroll
      for (int kvt = 0; kvt < 8; ++kvt) {
        half8 kf = *(const half8*)&sK[(kvt * 16 + lr) * 72 + ks * 32 + quad * 8];
        Sa[0][kvt] = mfma16(kf, qf[0][ks], Sa[0][kvt]);
        Sa[1][kvt] = mfma16(kf, qf[1][ks], Sa[1][kvt]);
      }
    }
    __builtin_amdgcn_s_setprio(0);

    if (jt == qt) {
#pragma unroll
      for (int qtl = 0; qtl < 2; ++qtl) {
        int q_loc = w * 32 + qtl * 16 + lr;
#pragma unroll
        for (int kvt = 0; kvt < 8; ++kvt) {
          int kv_base = kvt * 16 + quad * 4;
#pragma unroll
          for (int r = 0; r < 4; ++r)
            if (kv_base + r > q_loc) Sa[qtl][kvt][r] = -1e30f;
        }
      }
    }

#pragma unroll
    for (int qtl = 0; qtl < 2; ++qtl) {
      float mx = Sa[qtl][0][0];
#pragma unroll
      for (int kvt = 0; kvt < 8; ++kvt)
#pragma unroll
        for (int r = 0; r < 4; ++r) mx = fmaxf(mx, Sa[qtl][kvt][r]);
      mx = fmaxf(mx, __shfl_xor(mx, 16));
      mx = fmaxf(mx, __shfl_xor(mx, 32));
      float mnew = fmaxf(m_i[qtl], mx);
      if (!__all(mx <= m_i[qtl])) {  // defer-max: alpha==1 when all <=
        float alpha = __builtin_amdgcn_exp2f(m_i[qtl] - mnew);
        l_i[qtl] *= alpha;
#pragma unroll
        for (int dt = 0; dt < 4; ++dt) Oa[dt][qtl] *= alpha;
      }
      m_i[qtl] = mnew;
      float rs = 0.f;
#pragma unroll
      for (int kvt = 0; kvt < 8; ++kvt)
#pragma unroll
        for (int r = 0; r < 4; ++r) {
          float p = __builtin_amdgcn_exp2f(Sa[qtl][kvt][r] - mnew);
          Sa[qtl][kvt][r] = p;
          rs += p;
        }
      rs += __shfl_xor(rs, 16);
      rs += __shfl_xor(rs, 32);
      l_i[qtl] += rs;
    }

    __builtin_amdgcn_s_setprio(1);
#pragma unroll
    for (int kvt = 0; kvt < 8; ++kvt) {
      half4 vf[4];
#pragma unroll
      for (int dt = 0; dt < 4; ++dt)
        vf[dt] = *(const half4*)&sVt[(dt * 16 + lr) * 136 + kvt * 16 + quad * 4];
      half4 pf[2];
#pragma unroll
      for (int qtl = 0; qtl < 2; ++qtl) {
        pf[qtl][0] = (_Float16)Sa[qtl][kvt][0];
        pf[qtl][1] = (_Float16)Sa[qtl][kvt][1];
        pf[qtl][2] = (_Float16)Sa[qtl][kvt][2];
        pf[qtl][3] = (_Float16)Sa[qtl][kvt][3];
      }
#pragma unroll
      for (int dt = 0; dt < 4; ++dt)
#pragma unroll
        for (int qtl = 0; qtl < 2; ++qtl)
          Oa[dt][qtl] = mfma16k16(vf[dt], pf[qtl], Oa[dt][qtl]);
    }
    __builtin_amdgcn_s_setprio(0);
    __syncthreads();
  }

  float inv0 = 1.0f / l_i[0], inv1 = 1.0f / l_i[1];
#pragma unroll
  for (int dt = 0; dt < 4; ++dt)
#pragma unroll
    for (int qtl = 0; qtl < 2; ++qtl) {
      float inv = qtl ? inv1 : inv0;
      floatx4 o = Oa[dt][qtl];
      half4 hv;
      hv[0] = (_Float16)(o[0] * inv); hv[1] = (_Float16)(o[1] * inv);
      hv[2] = (_Float16)(o[2] * inv); hv[3] = (_Float16)(o[3] * inv);
      *(half4*)&sK[(w * 32 + qtl * 16 + lr) * 72 + dt * 16 + quad * 4] = hv;
    }
  __syncthreads();
#pragma unroll
  for (int it = 0; it < 2; ++it) {
    int row = (tid >> 2) + it * 64;
    int t = q0 + row;
    _Float16* orow = O + ((size_t)(bb * 2048 + t)) * 2048 + hh * 64;
#pragma unroll
    for (int cc = 0; cc < 2; ++cc) {
      int col = (tid & 3) * 16 + cc * 8;
      *(half8*)(orow + col) = *(const half8*)&sK[row * 72 + col];
    }
  }
}

// ---------------------------------------------------------------- launch
extern "C" void kernel_launch(void* const* d_in, const int* in_sizes, int n_in,
                              void* d_out, int out_size, void* d_ws, size_t ws_size,
                              hipStream_t stream) {
  (void)in_sizes; (void)n_in; (void)out_size; (void)ws_size;
  const float* x = (const float*)d_in[0];
  const float* Wqkv = (const float*)d_in[1];
  const float* bqkv = (const float*)d_in[2];
  const float* Wout = (const float*)d_in[3];
  const float* bout = (const float*)d_in[4];
  float* out = (float*)d_out;
  char* ws = (char*)d_ws;

  _Float16* xh    = (_Float16*)(ws + 0);
  _Float16* wqkvt = (_Float16*)(ws + 16777216);
  _Float16* Oh    = (_Float16*)(ws + 16777216);   // overlays wqkvt (dead)
  _Float16* Qh    = (_Float16*)(ws + 41943040);
  _Float16* Kh    = (_Float16*)(ws + 58720256);
  _Float16* Vth   = (_Float16*)(ws + 75497472);   // V^T
  _Float16* woutt = (_Float16*)(ws + 92274688);   // total 96 MB

  cvt_all_kernel<<<8192, 256, 0, stream>>>(x, xh, Wqkv, wqkvt, Wout, woutt);
  gemm_qkv_kernel<<<dim3(32, 16), 512, 0, stream>>>(xh, wqkvt, bqkv, Qh, Kh, Vth);
  attn_kernel<<<dim3(64, 16), 256, 0, stream>>>(Qh, Kh, Vth, Oh);
  gemm_out_kernel<<<dim3(16, 16), 512, 0, stream>>>(Oh, woutt, bout, out);
}

// Round 13
// 387.115 us; speedup vs baseline: 1.0095x; 1.0095x over previous
//
#include <hip/hip_runtime.h>

// MHA fused pipeline for MI355X (gfx950), f16 MFMA + fp32 accumulate.
// Round 20: consolidate to best-measured config (R16 = 386.3us) + XCD swizzle.
//  - attn: exact R16 body (one q-tile/block, grid 64x16, K+V register
//    prefetch, padded sK/sVt, NO defer-max -- R19's bundle was +4us).
//  - cvt: back to 3 separate kernels (R16 config; R19's fusion was within
//    the +4us bundle).
//  - gemm_qkv + gemm_out: XCD-aware block swizzle (T1). FETCH_SIZE shows
//    90MB vs 41MB ideal = 2.2x L2 over-fetch; the 1-barrier loop's per-tile
//    vmcnt(0) stall is latency-sensitive, and B-panel L2 residency (4 panels
//    x 768KB = 3MB < 4MB XCD L2 for qkv) converts HBM-latency waits into
//    L2-hit waits. Bijective: p=by*W+bx; k=p&7; q=p>>3; bx'=k+8*(q&A);
//    by'=q>>B with W=32:A=3,B=2 (512 blocks) / W=16:A=1,B=1 (256 blocks).
//  - gemm_out: 1-barrier 256x128 kernel (R17; measured neutral, 1 full round).
//
// ws layout (bytes):
//   xh     @ 0          : 4096x2048 f16  (x cast)
//   wqkvt  @ 16777216   : 6144x2048 f16  (Wqkv^T)   [dead after QKV gemm]
//   Oh     @ 16777216   : 4096x2048 f16  (attn out)  [overlays wqkvt]
//   Qh     @ 41943040   : [64 bh][2048][64] f16  (RoPE'd)
//   Kh     @ 58720256   : [64 bh][2048][64] f16  (RoPE'd)
//   Vth    @ 75497472   : [64 bh][64][2048] f16  (V^T)
//   woutt  @ 92274688   : 2048x2048 f16  (Wout^T)
//   total 100663296 B = 96 MB

typedef _Float16 half8 __attribute__((ext_vector_type(8)));
typedef _Float16 half4 __attribute__((ext_vector_type(4)));
typedef float floatx4 __attribute__((ext_vector_type(4)));

#define GLD_LDS16(gp, sp)                                        \
  __builtin_amdgcn_global_load_lds(                              \
      (__attribute__((address_space(1))) void*)(gp),             \
      (__attribute__((address_space(3))) void*)(sp), 16, 0, 0)

__device__ __forceinline__ floatx4 mfma16(half8 a, half8 b, floatx4 c) {
  return __builtin_amdgcn_mfma_f32_16x16x32_f16(a, b, c, 0, 0, 0);
}
__device__ __forceinline__ floatx4 mfma16k16(half4 a, half4 b, floatx4 c) {
  return __builtin_amdgcn_mfma_f32_16x16x16f16(a, b, c, 0, 0, 0);
}

// ---------------------------------------------------------------- cvt_x
__global__ __launch_bounds__(256) void cvt_x_kernel(const float* __restrict__ x,
                                                    _Float16* __restrict__ xh) {
  int idx = blockIdx.x * 256 + threadIdx.x;  // 8 elems each, 8.4M total
  const floatx4* p = (const floatx4*)x + (size_t)idx * 2;
  floatx4 a = p[0], b = p[1];
  half8 o;
#pragma unroll
  for (int j = 0; j < 4; ++j) { o[j] = (_Float16)a[j]; o[4 + j] = (_Float16)b[j]; }
  *((half8*)xh + idx) = o;
}

// ------------------------------------------------------- cvt + transpose W
// W (Kd x Nd) f32 row-major  ->  Wt (Nd x Kd) f16 row-major
__global__ __launch_bounds__(256) void cvt_wt_kernel(const float* __restrict__ W,
                                                     _Float16* __restrict__ Wt,
                                                     int Kd, int Nd) {
  __shared__ float tile[64][65];
  int n0 = blockIdx.x * 64, k0 = blockIdx.y * 64;
  int tid = threadIdx.x;
#pragma unroll
  for (int it = 0; it < 4; ++it) {
    int r = (tid >> 4) + it * 16;   // k-local
    int c = (tid & 15) * 4;         // n-local
    floatx4 v = *(const floatx4*)(W + (size_t)(k0 + r) * Nd + n0 + c);
    tile[r][c + 0] = v[0]; tile[r][c + 1] = v[1];
    tile[r][c + 2] = v[2]; tile[r][c + 3] = v[3];
  }
  __syncthreads();
#pragma unroll
  for (int it = 0; it < 2; ++it) {
    int r = (tid >> 3) + it * 32;   // n-local
    int c = (tid & 7) * 8;          // k-local
    half8 o;
#pragma unroll
    for (int j = 0; j < 8; ++j) o[j] = (_Float16)tile[c + j][r];
    *(half8*)(Wt + (size_t)(n0 + r) * Kd + k0 + c) = o;
  }
}

// --------------------------------------------- 256x192 1-barrier GEMM (QKV)
// C(256x192) = A(4096x2048) @ Bt(6144x2048)^T + bias, QKV epilogue.
// 8 waves = 4M x 2N; grid 32x16 = 512 blocks = 2 full rounds.
// XCD swizzle: each XCD owns 4 B-panels (3MB, L2-resident) x all M rows.
__global__ __launch_bounds__(512, 2) void gemm_qkv_kernel(
    const _Float16* __restrict__ A, const _Float16* __restrict__ Bt,
    const float* __restrict__ bias,
    _Float16* __restrict__ Qd, _Float16* __restrict__ Kkd,
    _Float16* __restrict__ Vd) {
  __shared__ __align__(16) _Float16 sA[2][16384];   // 256 x 64
  __shared__ __align__(16) _Float16 sB[2][12288];   // 192 x 64
  constexpr int KD = 2048;
  constexpr int NT = KD / 64;  // 32 K-tiles

  int tid = threadIdx.x, w = tid >> 6, l = tid & 63;
  int lr = l & 15, quad = l >> 4;
  int wr = w >> 1, wc = w & 1;
  // XCD-aware remap: dispatch block p (lands on XCD p%8) computes tile
  // (bx, by) = (k + 8*(q&3), q>>2), k=p&7, q=p>>3. Bijective for 512 blocks.
  int p = blockIdx.y * 32 + blockIdx.x;
  int kx = p & 7, q = p >> 3;
  int bx = kx + 8 * (q & 3), by = q >> 2;
  int m0 = by * 256, n0 = bx * 192;

  int csw0 = ((quad) ^ (lr & 7)) * 8;
  int csw1 = ((quad + 4) ^ (lr & 7)) * 8;

  const _Float16* pA[4];
  const _Float16* pB[3];
  {
    int rl = l >> 3;
    int cs = ((l & 7) ^ rl) * 8;
#pragma unroll
    for (int jj = 0; jj < 4; ++jj)
      pA[jj] = A + (size_t)(m0 + w * 32 + jj * 8 + rl) * KD + cs;
#pragma unroll
    for (int jj = 0; jj < 3; ++jj)
      pB[jj] = Bt + (size_t)(n0 + w * 24 + jj * 8 + rl) * KD + cs;
  }

#define STAGE_ALL(BUF, KT)                                                   \
  _Pragma("unroll") for (int jj = 0; jj < 4; ++jj)                           \
    GLD_LDS16(pA[jj] + (KT), &sA[BUF][(w * 32 + jj * 8) * 64]);              \
  _Pragma("unroll") for (int jj = 0; jj < 3; ++jj)                           \
    GLD_LDS16(pB[jj] + (KT), &sB[BUF][(w * 24 + jj * 8) * 64]);

  floatx4 z4 = {0.f, 0.f, 0.f, 0.f};
  floatx4 acc[4][6];
#pragma unroll
  for (int i = 0; i < 4; ++i)
#pragma unroll
    for (int j = 0; j < 6; ++j) acc[i][j] = z4;

  STAGE_ALL(0, 0);
  asm volatile("s_waitcnt vmcnt(0)" ::: "memory");
  __builtin_amdgcn_s_barrier();

  half8 af[4][2], bf[6][2];
#pragma unroll 2
  for (int t = 0; t < NT; ++t) {
    int buf = t & 1, nbuf = buf ^ 1;
    if (t + 1 < NT) { STAGE_ALL(nbuf, (t + 1) * 64); }
#pragma unroll
    for (int j = 0; j < 6; ++j) {
      int row_ = wc * 96 + j * 16 + lr;
      bf[j][0] = *(const half8*)&sB[buf][row_ * 64 + csw0];
      bf[j][1] = *(const half8*)&sB[buf][row_ * 64 + csw1];
    }
#pragma unroll
    for (int i = 0; i < 4; ++i) {
      int row_ = wr * 64 + i * 16 + lr;
      af[i][0] = *(const half8*)&sA[buf][row_ * 64 + csw0];
      af[i][1] = *(const half8*)&sA[buf][row_ * 64 + csw1];
    }
    __builtin_amdgcn_s_setprio(1);
#pragma unroll
    for (int j = 0; j < 6; ++j)
#pragma unroll
      for (int ks = 0; ks < 2; ++ks)
#pragma unroll
        for (int i = 0; i < 4; ++i)
          acc[i][j] = mfma16(af[i][ks], bf[j][ks], acc[i][j]);
    __builtin_amdgcn_s_setprio(0);
    asm volatile("s_waitcnt vmcnt(0)" ::: "memory");
    __builtin_amdgcn_s_barrier();
  }

  // ---- epilogue. C/D layout: col = lane&15, row = quad*4 + r.
  float bj[6];
#pragma unroll
  for (int j = 0; j < 6; ++j) bj[j] = bias[n0 + wc * 96 + j * 16 + lr];
  float freq = __expf(-(float)lr * 0.57564627324851148f);  // 10000^(-lr/16)
#pragma unroll
  for (int j = 0; j < 6; ++j) {
    int cb = wc * 96 + j * 16;
    int cg = n0 + cb;
    int which = cg >> 11;
    int d0 = cb & 63;  // n0 is 64-aligned (192*bx)
    int hh = (cg & 2047) >> 6;
    if (which == 2) {
      int dd = d0 + lr;
#pragma unroll
      for (int i = 0; i < 4; ++i) {
        int m = m0 + wr * 64 + i * 16 + quad * 4;
        int bb = m >> 11, tt = m & 2047;
        half4 h;
#pragma unroll
        for (int r = 0; r < 4; ++r) h[r] = (_Float16)(acc[i][j][r] + bj[j]);
        *(half4*)&Vd[(((size_t)(bb * 32 + hh)) * 64 + dd) * 2048 + tt] = h;
      }
    } else if (d0 == 0) {
      _Float16* dst = which ? Kkd : Qd;
#pragma unroll
      for (int i = 0; i < 4; ++i)
#pragma unroll
        for (int r = 0; r < 4; ++r) {
          int m = m0 + wr * 64 + i * 16 + quad * 4 + r;
          int bb = m >> 11, tt = m & 2047;
          float sn, cs2;
          __sincosf((float)tt * freq, &sn, &cs2);
          float x1 = acc[i][j][r] + bj[j];
          float x2 = acc[i][j + 1][r] + bj[j + 1];
          _Float16* row = dst + ((size_t)(bb * 32 + hh) * 2048 + (size_t)tt) * 64;
          row[lr] = (_Float16)(x1 * cs2 - x2 * sn);
          row[lr + 16] = (_Float16)(x1 * sn + x2 * cs2);
        }
    } else if (d0 >= 32) {
      _Float16* dst = which ? Kkd : Qd;
#pragma unroll
      for (int i = 0; i < 4; ++i)
#pragma unroll
        for (int r = 0; r < 4; ++r) {
          int m = m0 + wr * 64 + i * 16 + quad * 4 + r;
          int bb = m >> 11, tt = m & 2047;
          _Float16* row = dst + ((size_t)(bb * 32 + hh) * 2048 + (size_t)tt) * 64;
          row[d0 + lr] = (_Float16)(acc[i][j][r] + bj[j]);
        }
    }
  }
#undef STAGE_ALL
}

// --------------------------------------------- 256x128 1-barrier GEMM (out)
// Co(4096x2048 f32) = A(4096x2048) @ Bt(2048x2048)^T + bias.
// 8 waves = 4M x 2N (wave tile 64x64); grid 16x16 = 256 blocks = 1 round.
// XCD swizzle: each XCD owns 2 B-panels (1MB, L2-resident) x all M rows.
__global__ __launch_bounds__(512, 2) void gemm_out_kernel(
    const _Float16* __restrict__ A, const _Float16* __restrict__ Bt,
    const float* __restrict__ bias, float* __restrict__ Co) {
  __shared__ __align__(16) _Float16 sA[2][16384];  // 256 x 64
  __shared__ __align__(16) _Float16 sB[2][8192];   // 128 x 64
  constexpr int KD = 2048;
  constexpr int NT = KD / 64;

  int tid = threadIdx.x, w = tid >> 6, l = tid & 63;
  int lr = l & 15, quad = l >> 4;
  int wr = w >> 1, wc = w & 1;
  int p = blockIdx.y * 16 + blockIdx.x;
  int kx = p & 7, q = p >> 3;
  int bx = kx + 8 * (q & 1), by = q >> 1;
  int m0 = by * 256, n0 = bx * 128;

  int csw0 = ((quad) ^ (lr & 7)) * 8;
  int csw1 = ((quad + 4) ^ (lr & 7)) * 8;

  const _Float16* pA[4];
  const _Float16* pB[2];
  {
    int rl = l >> 3;
    int cs = ((l & 7) ^ rl) * 8;
#pragma unroll
    for (int jj = 0; jj < 4; ++jj)
      pA[jj] = A + (size_t)(m0 + w * 32 + jj * 8 + rl) * KD + cs;
#pragma unroll
    for (int jj = 0; jj < 2; ++jj)
      pB[jj] = Bt + (size_t)(n0 + w * 16 + jj * 8 + rl) * KD + cs;
  }

#define STAGE_O(BUF, KT)                                                     \
  _Pragma("unroll") for (int jj = 0; jj < 4; ++jj)                           \
    GLD_LDS16(pA[jj] + (KT), &sA[BUF][(w * 32 + jj * 8) * 64]);              \
  _Pragma("unroll") for (int jj = 0; jj < 2; ++jj)                           \
    GLD_LDS16(pB[jj] + (KT), &sB[BUF][(w * 16 + jj * 8) * 64]);

  floatx4 z4 = {0.f, 0.f, 0.f, 0.f};
  floatx4 acc[4][4];
#pragma unroll
  for (int i = 0; i < 4; ++i)
#pragma unroll
    for (int j = 0; j < 4; ++j) acc[i][j] = z4;

  STAGE_O(0, 0);
  asm volatile("s_waitcnt vmcnt(0)" ::: "memory");
  __builtin_amdgcn_s_barrier();

  half8 af[4][2], bf[4][2];
#pragma unroll 2
  for (int t = 0; t < NT; ++t) {
    int buf = t & 1, nbuf = buf ^ 1;
    if (t + 1 < NT) { STAGE_O(nbuf, (t + 1) * 64); }
#pragma unroll
    for (int j = 0; j < 4; ++j) {
      int row_ = wc * 64 + j * 16 + lr;
      bf[j][0] = *(const half8*)&sB[buf][row_ * 64 + csw0];
      bf[j][1] = *(const half8*)&sB[buf][row_ * 64 + csw1];
    }
#pragma unroll
    for (int i = 0; i < 4; ++i) {
      int row_ = wr * 64 + i * 16 + lr;
      af[i][0] = *(const half8*)&sA[buf][row_ * 64 + csw0];
      af[i][1] = *(const half8*)&sA[buf][row_ * 64 + csw1];
    }
    __builtin_amdgcn_s_setprio(1);
#pragma unroll
    for (int j = 0; j < 4; ++j)
#pragma unroll
      for (int ks = 0; ks < 2; ++ks)
#pragma unroll
        for (int i = 0; i < 4; ++i)
          acc[i][j] = mfma16(af[i][ks], bf[j][ks], acc[i][j]);
    __builtin_amdgcn_s_setprio(0);
    asm volatile("s_waitcnt vmcnt(0)" ::: "memory");
    __builtin_amdgcn_s_barrier();
  }

#pragma unroll
  for (int j = 0; j < 4; ++j) {
    int n = n0 + wc * 64 + j * 16 + lr;
    float bj = bias[n];
#pragma unroll
    for (int i = 0; i < 4; ++i)
#pragma unroll
      for (int r = 0; r < 4; ++r) {
        int m = m0 + wr * 64 + i * 16 + quad * 4 + r;
        Co[(size_t)m * 2048 + n] = acc[i][j][r] + bj;
      }
  }
#undef STAGE_O
}

// ---------------------------------------------------------------- attention
// Flash-style causal attention, S^T formulation + register prefetch.
// Exact R16 body (best measured): one 128-row q-tile per block; grid 64x16,
// qt = 15 - blockIdx.y (long blocks first); 3 blocks/CU (VGPR 148).
__global__ __launch_bounds__(256) void attn_kernel(
    const _Float16* __restrict__ Q, const _Float16* __restrict__ Kk,
    const _Float16* __restrict__ Vt, _Float16* __restrict__ O) {
  constexpr int S = 2048;
  int bh = blockIdx.x;
  int qt = 15 - blockIdx.y;  // long blocks first
  int bb = bh >> 5, hh = bh & 31;
  const _Float16* Qb = Q + (size_t)bh * S * 64;
  const _Float16* Kb = Kk + (size_t)bh * S * 64;
  const _Float16* Vb = Vt + (size_t)bh * 64 * S;

  __shared__ __align__(16) _Float16 sK[128 * 72];   // [kv][64+pad], reused as sO
  __shared__ __align__(16) _Float16 sVt[64 * 136];  // [d][128+pad]

  int tid = threadIdx.x, w = tid >> 6, l = tid & 63;
  int lr = l & 15, quad = l >> 4;

  int rk = tid >> 3, ck = (tid & 7) * 8;   // K: 32 rows x 64d per pass
  int rv = tid >> 4, cv = (tid & 15) * 8;  // Vt: 16 rows x 128kv per pass
  const _Float16* Kst = Kb + (size_t)rk * 64 + ck;
  const _Float16* Vst = Vb + (size_t)rv * S + cv;

  floatx4 z4 = {0.f, 0.f, 0.f, 0.f};
  int q0 = qt * 128;

  half8 qf[2][2];  // [qtile][ks]
#pragma unroll
  for (int qtl = 0; qtl < 2; ++qtl)
#pragma unroll
    for (int ks = 0; ks < 2; ++ks) {
      half8 v = *(const half8*)(Qb + (size_t)(q0 + w * 32 + qtl * 16 + lr) * 64 +
                                ks * 32 + quad * 8);
      qf[qtl][ks] = v * (_Float16)0.18033688f;  // 0.125 * log2(e)
    }

  floatx4 Oa[4][2];
  float m_i[2] = {-1e30f, -1e30f}, l_i[2] = {0.f, 0.f};
#pragma unroll
  for (int dt = 0; dt < 4; ++dt)
#pragma unroll
    for (int qtl = 0; qtl < 2; ++qtl) Oa[dt][qtl] = z4;

  half8 kpre[4], vpre[4];
#pragma unroll
  for (int it = 0; it < 4; ++it) {
    kpre[it] = *(const half8*)(Kst + (size_t)it * 32 * 64);
    vpre[it] = *(const half8*)(Vst + (size_t)it * 16 * S);
  }

  for (int jt = 0; jt <= qt; ++jt) {
#pragma unroll
    for (int it = 0; it < 4; ++it) {
      *(half8*)&sK[(rk + it * 32) * 72 + ck] = kpre[it];
      *(half8*)&sVt[(rv + it * 16) * 136 + cv] = vpre[it];
    }
    if (jt < qt) {
      int kv1 = (jt + 1) * 128;
#pragma unroll
      for (int it = 0; it < 4; ++it) {
        kpre[it] = *(const half8*)(Kst + (size_t)(kv1 + it * 32) * 64);
        vpre[it] = *(const half8*)(Vst + kv1 + (size_t)it * 16 * S);
      }
    }
    __syncthreads();

    floatx4 Sa[2][8];
#pragma unroll
    for (int qtl = 0; qtl < 2; ++qtl)
#pragma unroll
      for (int kvt = 0; kvt < 8; ++kvt) Sa[qtl][kvt] = z4;
    __builtin_amdgcn_s_setprio(1);
#pragma unroll
    for (int ks = 0; ks < 2; ++ks) {
#pragma unroll
      for (int kvt = 0; kvt < 8; ++kvt) {
        half8 kf = *(const half8*)&sK[(kvt * 16 + lr) * 72 + ks * 32 + quad * 8];
        Sa[0][kvt] = mfma16(kf, qf[0][ks], Sa[0][kvt]);
        Sa[1][kvt] = mfma16(kf, qf[1][ks], Sa[1][kvt]);
      }
    }
    __builtin_amdgcn_s_setprio(0);

    if (jt == qt) {
#pragma unroll
      for (int qtl = 0; qtl < 2; ++qtl) {
        int q_loc = w * 32 + qtl * 16 + lr;
#pragma unroll
        for (int kvt = 0; kvt < 8; ++kvt) {
          int kv_base = kvt * 16 + quad * 4;
#pragma unroll
          for (int r = 0; r < 4; ++r)
            if (kv_base + r > q_loc) Sa[qtl][kvt][r] = -1e30f;
        }
      }
    }

#pragma unroll
    for (int qtl = 0; qtl < 2; ++qtl) {
      float mx = Sa[qtl][0][0];
#pragma unroll
      for (int kvt = 0; kvt < 8; ++kvt)
#pragma unroll
        for (int r = 0; r < 4; ++r) mx = fmaxf(mx, Sa[qtl][kvt][r]);
      mx = fmaxf(mx, __shfl_xor(mx, 16));
      mx = fmaxf(mx, __shfl_xor(mx, 32));
      float mnew = fmaxf(m_i[qtl], mx);
      float alpha = __builtin_amdgcn_exp2f(m_i[qtl] - mnew);
      m_i[qtl] = mnew;
      float rs = 0.f;
#pragma unroll
      for (int kvt = 0; kvt < 8; ++kvt)
#pragma unroll
        for (int r = 0; r < 4; ++r) {
          float p = __builtin_amdgcn_exp2f(Sa[qtl][kvt][r] - mnew);
          Sa[qtl][kvt][r] = p;
          rs += p;
        }
      rs += __shfl_xor(rs, 16);
      rs += __shfl_xor(rs, 32);
      l_i[qtl] = l_i[qtl] * alpha + rs;
#pragma unroll
      for (int dt = 0; dt < 4; ++dt) Oa[dt][qtl] *= alpha;
    }

    __builtin_amdgcn_s_setprio(1);
#pragma unroll
    for (int kvt = 0; kvt < 8; ++kvt) {
      half4 vf[4];
#pragma unroll
      for (int dt = 0; dt < 4; ++dt)
        vf[dt] = *(const half4*)&sVt[(dt * 16 + lr) * 136 + kvt * 16 + quad * 4];
      half4 pf[2];
#pragma unroll
      for (int qtl = 0; qtl < 2; ++qtl) {
        pf[qtl][0] = (_Float16)Sa[qtl][kvt][0];
        pf[qtl][1] = (_Float16)Sa[qtl][kvt][1];
        pf[qtl][2] = (_Float16)Sa[qtl][kvt][2];
        pf[qtl][3] = (_Float16)Sa[qtl][kvt][3];
      }
#pragma unroll
      for (int dt = 0; dt < 4; ++dt)
#pragma unroll
        for (int qtl = 0; qtl < 2; ++qtl)
          Oa[dt][qtl] = mfma16k16(vf[dt], pf[qtl], Oa[dt][qtl]);
    }
    __builtin_amdgcn_s_setprio(0);
    __syncthreads();
  }

  float inv0 = 1.0f / l_i[0], inv1 = 1.0f / l_i[1];
#pragma unroll
  for (int dt = 0; dt < 4; ++dt)
#pragma unroll
    for (int qtl = 0; qtl < 2; ++qtl) {
      float inv = qtl ? inv1 : inv0;
      floatx4 o = Oa[dt][qtl];
      half4 hv;
      hv[0] = (_Float16)(o[0] * inv); hv[1] = (_Float16)(o[1] * inv);
      hv[2] = (_Float16)(o[2] * inv); hv[3] = (_Float16)(o[3] * inv);
      *(half4*)&sK[(w * 32 + qtl * 16 + lr) * 72 + dt * 16 + quad * 4] = hv;
    }
  __syncthreads();
#pragma unroll
  for (int it = 0; it < 2; ++it) {
    int row = (tid >> 2) + it * 64;
    int t = q0 + row;
    _Float16* orow = O + ((size_t)(bb * 2048 + t)) * 2048 + hh * 64;
#pragma unroll
    for (int cc = 0; cc < 2; ++cc) {
      int col = (tid & 3) * 16 + cc * 8;
      *(half8*)(orow + col) = *(const half8*)&sK[row * 72 + col];
    }
  }
}

// ---------------------------------------------------------------- launch
extern "C" void kernel_launch(void* const* d_in, const int* in_sizes, int n_in,
                              void* d_out, int out_size, void* d_ws, size_t ws_size,
                              hipStream_t stream) {
  (void)in_sizes; (void)n_in; (void)out_size; (void)ws_size;
  const float* x = (const float*)d_in[0];
  const float* Wqkv = (const float*)d_in[1];
  const float* bqkv = (const float*)d_in[2];
  const float* Wout = (const float*)d_in[3];
  const float* bout = (const float*)d_in[4];
  float* out = (float*)d_out;
  char* ws = (char*)d_ws;

  _Float16* xh    = (_Float16*)(ws + 0);
  _Float16* wqkvt = (_Float16*)(ws + 16777216);
  _Float16* Oh    = (_Float16*)(ws + 16777216);   // overlays wqkvt (dead)
  _Float16* Qh    = (_Float16*)(ws + 41943040);
  _Float16* Kh    = (_Float16*)(ws + 58720256);
  _Float16* Vth   = (_Float16*)(ws + 75497472);   // V^T
  _Float16* woutt = (_Float16*)(ws + 92274688);   // total 96 MB

  cvt_x_kernel<<<4096, 256, 0, stream>>>(x, xh);
  cvt_wt_kernel<<<dim3(96, 32), 256, 0, stream>>>(Wqkv, wqkvt, 2048, 6144);
  cvt_wt_kernel<<<dim3(32, 32), 256, 0, stream>>>(Wout, woutt, 2048, 2048);
  gemm_qkv_kernel<<<dim3(32, 16), 512, 0, stream>>>(xh, wqkvt, bqkv, Qh, Kh, Vth);
  attn_kernel<<<dim3(64, 16), 256, 0, stream>>>(Qh, Kh, Vth, Oh);
  gemm_out_kernel<<<dim3(16, 16), 512, 0, stream>>>(Oh, woutt, bout, out);
}